// Round 22
// baseline (1589.062 us; speedup 1.0000x reference)
//
#include <hip/hip_runtime.h>
#include <hip/hip_bf16.h>
#include <math.h>

// EventTransformer on MI355X — round 22: round-21 (best, 1573us) with mattn
// widened to 8 independent waves/block (512 thr, QF=1, VGPR unchanged at 64;
// q-tiles of 128 -> half the blocks, fewer early-exits). Everything else
// identical to round 21.

#define D_INPUT  128
#define DM       256
#define NHEADS   4
#define HDIM     64
#define NLAYERS  4
#define DFF      1024
#define BEV      128
#define LNEPS    1e-5f
#define KT       10      // key tiles of 64 per (b,h): covers Sb <= 640
#define QTQ      5       // q-tiles of 128 per (b,h)
#define SCL      0.18033688011112042f   // 0.125 * log2(e)

typedef unsigned short u16;
typedef __attribute__((ext_vector_type(8))) short bf16x8;
typedef __attribute__((ext_vector_type(4))) float f32x4;

__device__ inline u16 f2bf(float x) {
    unsigned int xi = __float_as_uint(x);
    unsigned int r  = xi + 0x7FFFu + ((xi >> 16) & 1u);   // RNE
    return (u16)(r >> 16);
}
__device__ inline unsigned int cvtpk(float lo, float hi) {
    unsigned int r;
    asm("v_cvt_pk_bf16_f32 %0, %1, %2" : "=v"(r) : "v"(lo), "v"(hi));
    return r;
}
__device__ inline float fexp2(float x) { return __builtin_amdgcn_exp2f(x); }

// Packed-activation element offset (u16 units). Matrix (rows x K), nkt=K/64.
// Fragment read: base + ((row>>4)*nkt + kt)*1024 + kk*512 + lane*8.
__device__ inline size_t apack(int row, int col, int nkt) {
    return ((size_t)(row >> 4) * nkt + (col >> 6)) * 1024
         + ((col >> 5) & 1) * 512
         + ((((col >> 3) & 3) * 16 + (row & 15)) * 8) + (col & 7);
}
// Packed-weight offset (identical formula; col = output col, row = k).
__device__ inline size_t wpack_off(int col, int k, int nkt) {
    const int c16 = col >> 4, llo = col & 15;
    const int kt = k >> 6, kr = k & 63;
    const int kk = kr >> 5, lhi = (kr >> 3) & 3, e = kr & 7;
    return ((size_t)(c16 * nkt + kt)) * 1024 + kk * 512 + (lhi * 16 + llo) * 8 + e;
}

// ---------------- prep kernels ----------------

__global__ void starts_kernel(const int* __restrict__ idx, int* __restrict__ counts,
                              int* __restrict__ starts, int N) {
    __shared__ int bnd[BEV + 1];
    const int b = threadIdx.x;
    if (b <= BEV) {
        int lo = 0, hi = N;
        while (lo < hi) { int mid = (lo + hi) >> 1; if (idx[mid] < b) lo = mid + 1; else hi = mid; }
        bnd[b] = lo;
    }
    __syncthreads();
    if (b < BEV) { starts[b] = bnd[b]; counts[b] = bnd[b + 1] - bnd[b]; }
}

__global__ void r2bs_kernel(const int* __restrict__ idx, const int* __restrict__ starts,
                            int* __restrict__ r2bs, int N, int TP) {
    int i = blockIdx.x * blockDim.x + threadIdx.x;
    if (i < N) {
        int b = idx[i];
        r2bs[i] = (b << 16) | (i - starts[b] + 1);
    } else if (i < N + BEV) {
        r2bs[i] = (i - N) << 16;
    } else if (i < TP) {
        r2bs[i] = BEV << 16;
    }
}

__global__ void beacon_kernel(float* out, int n, float v) {
    int i = blockIdx.x * blockDim.x + threadIdx.x;
    if (i < n) out[i] = v;
}

// fp32 -> bf16 + fragment packing of all 4 weight groups
__global__ void cvt4p_kernel(const float* __restrict__ s0, const float* __restrict__ s1,
                             const float* __restrict__ s2, const float* __restrict__ s3,
                             u16* __restrict__ d0, u16* __restrict__ d1,
                             u16* __restrict__ d2, u16* __restrict__ d3) {
    const int n0 = NLAYERS * 768 * 256, n1 = NLAYERS * 256 * 256;
    const int n2 = NLAYERS * 1024 * 256, n3 = NLAYERS * 256 * 1024;
    int i = blockIdx.x * blockDim.x + threadIdx.x;
    if (i < n0) {
        const int NoK = 768 * 256;
        int l = i / NoK, rem = i - l * NoK, col = rem >> 8, k = rem & 255;
        d0[(size_t)l * NoK + wpack_off(col, k, 4)] = f2bf(s0[i]);
        return;
    }
    i -= n0;
    if (i < n1) {
        const int NoK = 256 * 256;
        int l = i / NoK, rem = i - l * NoK, col = rem >> 8, k = rem & 255;
        d1[(size_t)l * NoK + wpack_off(col, k, 4)] = f2bf(s1[i]);
        return;
    }
    i -= n1;
    if (i < n2) {
        const int NoK = 1024 * 256;
        int l = i / NoK, rem = i - l * NoK, col = rem >> 8, k = rem & 255;
        d2[(size_t)l * NoK + wpack_off(col, k, 4)] = f2bf(s2[i]);
        return;
    }
    i -= n2;
    if (i < n3) {
        const int NoK = 256 * 1024;
        int l = i / NoK, rem = i - l * NoK, col = rem >> 10, k = rem & 1023;
        d3[(size_t)l * NoK + wpack_off(col, k, 16)] = f2bf(s3[i]);
    }
}

// We (256 x 384) packed = [in_proj_w | geo_proj_w[:, :252] | 0]; be = in_b+geo_b
__global__ void prep_w_kernel(const float* __restrict__ win, const float* __restrict__ wgeo,
                              const float* __restrict__ bin, const float* __restrict__ bgeo,
                              u16* __restrict__ We, float* __restrict__ be) {
    int i = blockIdx.x * blockDim.x + threadIdx.x;
    if (i < 256 * 384) {
        int o = i / 384, k = i % 384;
        float v = 0.f;
        if (k < 128)      v = win[o * 128 + k];
        else if (k < 380) v = wgeo[o * 256 + (k - 128)];
        We[wpack_off(o, k, 6)] = f2bf(v);
    }
    if (i < 256) be[i] = bin[i] + bgeo[i];
}

// A (N x 384) PACKED bf16 = [dom_embeddings | pos_enc (252) | 0]; 4 cols/thread.
__global__ void prep_a_kernel(const float* __restrict__ emb, const float* __restrict__ geo,
                              u16* __restrict__ Ap, int N) {
    size_t t = (size_t)blockIdx.x * blockDim.x + threadIdx.x;
    if (t >= (size_t)N * 96) return;
    const int c4 = (int)(t % 96) * 4;
    const size_t r = t / 96;
    float v[4];
    #pragma unroll
    for (int u = 0; u < 4; ++u) {
        const int k = c4 + u;
        float x = 0.f;
        if (k < 128) {
            x = emb[r * 128 + k];
        } else if (k < 380) {
            int rem  = k - 128;
            int axis = rem / 84;
            int r2   = rem % 84;
            int band = r2 >> 1;
            int sc   = r2 & 1;
            float freq = expf((float)band * (2.3025850929940457f / 41.0f)); // 10^(band/41)
            float ang  = (6.283185307179586f * geo[r * 3 + axis]) * freq;
            x = sc ? cosf(ang) : sinf(ang);
        }
        v[u] = x;
    }
    uint2 pp;
    pp.x = cvtpk(v[0], v[1]);
    pp.y = cvtpk(v[2], v[3]);
    *(uint2*)&Ap[apack((int)r, c4, 6)] = pp;
}

__global__ void cls_kernel(const float* __restrict__ cls, float* __restrict__ h, int N) {
    h[(size_t)(N + blockIdx.x) * DM + threadIdx.x] = cls[threadIdx.x];
}

// ---------------- layernorm (layer-0 ln1 only), PACKED output ----------------

__global__ __launch_bounds__(256) void ln_kernel(const float* __restrict__ x,
                                                 const float* __restrict__ w,
                                                 const float* __restrict__ b,
                                                 u16* __restrict__ yp, int T) {
    int row  = blockIdx.x * 4 + (threadIdx.x >> 6);
    int lane = threadIdx.x & 63;
    if (row >= T) return;
    float4 v = ((const float4*)(x + (size_t)row * DM))[lane];
    float s = v.x + v.y + v.z + v.w;
    #pragma unroll
    for (int off = 32; off > 0; off >>= 1) s += __shfl_xor(s, off);
    float mean = s * (1.0f / 256.0f);
    float dx = v.x - mean, dy = v.y - mean, dz = v.z - mean, dw = v.w - mean;
    float ss = dx * dx + dy * dy + dz * dz + dw * dw;
    #pragma unroll
    for (int off = 32; off > 0; off >>= 1) ss += __shfl_xor(ss, off);
    float inv = rsqrtf(ss * (1.0f / 256.0f) + LNEPS);
    float4 wv = ((const float4*)w)[lane];
    float4 bv = ((const float4*)b)[lane];
    const int col0 = lane * 4;
    uint2 yy;
    yy.x = cvtpk(dx * inv * wv.x + bv.x, dy * inv * wv.y + bv.y);
    yy.y = cvtpk(dz * inv * wv.z + bv.z, dw * inv * wv.w + bv.w);
    *(uint2*)&yp[apack(row, col0, 4)] = yy;
}

// ---------------- barrier-free packed GEMM: 64 rows x 256 cols, 256 thr ----------------
// MODE 0: C = X@W^T + bias (f32 row-major, embed).
// MODE 1: qkv split (n0==0 -> Q row-major *SCL; 256 -> K tiled; 512 -> V tiled).
// MODE 2: ff1 -> relu, packed bf16 output (nkt_out=16) into Qb arg.

template <int MODE>
__global__ __launch_bounds__(256) void pgemm_kernel(const u16* __restrict__ Xp,
                                                    const u16* __restrict__ Wp,
                                                    const float* __restrict__ bias,
                                                    float* __restrict__ C,
                                                    u16* __restrict__ Qb,
                                                    u16* __restrict__ KVt,
                                                    const int* __restrict__ r2bs,
                                                    int nkt) {
    const int m0 = blockIdx.y * 64, n0 = blockIdx.x * 256;
    const int tid = threadIdx.x, wv = tid >> 6, lane = tid & 63;
    const int lhi = lane >> 4, llo = lane & 15;
    const int rt0 = m0 >> 4;

    f32x4 acc[4][4];
    #pragma unroll
    for (int i = 0; i < 4; ++i)
        #pragma unroll
        for (int j = 0; j < 4; ++j) acc[i][j] = (f32x4){0.f, 0.f, 0.f, 0.f};

    for (int kt = 0; kt < nkt; ++kt) {
        #pragma unroll
        for (int kk = 0; kk < 2; ++kk) {
            bf16x8 xf[4], wf[4];
            #pragma unroll
            for (int i = 0; i < 4; ++i)
                xf[i] = *(const bf16x8*)(Xp + ((size_t)(rt0 + i) * nkt + kt) * 1024
                                         + kk * 512 + lane * 8);
            #pragma unroll
            for (int j = 0; j < 4; ++j) {
                const int c16 = (n0 >> 4) + wv * 4 + j;
                wf[j] = *(const bf16x8*)(Wp + ((size_t)c16 * nkt + kt) * 1024
                                         + kk * 512 + lane * 8);
            }
            #pragma unroll
            for (int i = 0; i < 4; ++i)
                #pragma unroll
                for (int j = 0; j < 4; ++j)
                    acc[i][j] = __builtin_amdgcn_mfma_f32_16x16x32_bf16(wf[j], xf[i], acc[i][j], 0, 0, 0);
        }
    }

    #pragma unroll
    for (int i = 0; i < 4; ++i) {
        const int row = m0 + i * 16 + llo;
        int eb = 0, pos = 0, ktile = KT;
        if (MODE == 1 && n0 >= 256) {
            const int bs = r2bs[row];
            eb = bs >> 16; pos = bs & 0xffff; ktile = pos >> 6;
        }
        #pragma unroll
        for (int j = 0; j < 4; ++j) {
            const int col0 = n0 + wv * 64 + j * 16 + lhi * 4;
            const float4 bb = *(const float4*)&bias[col0];
            const float v0 = acc[i][j][0] + bb.x, v1 = acc[i][j][1] + bb.y;
            const float v2 = acc[i][j][2] + bb.z, v3 = acc[i][j][3] + bb.w;
            if (MODE == 0) {
                float4 c = {v0, v1, v2, v3};
                *(float4*)&C[(size_t)row * 256 + col0] = c;
            } else if (MODE == 2) {
                uint2 yy;
                yy.x = cvtpk(fmaxf(v0, 0.f), fmaxf(v1, 0.f));
                yy.y = cvtpk(fmaxf(v2, 0.f), fmaxf(v3, 0.f));
                *(uint2*)&Qb[apack(row, col0, 16)] = yy;
            } else if (n0 == 0) {
                uint2 q;
                q.x = cvtpk(v0 * SCL, v1 * SCL);
                q.y = cvtpk(v2 * SCL, v3 * SCL);
                *(uint2*)&Qb[(size_t)row * 256 + col0] = q;
            } else if (n0 == 256) {
                if (ktile < KT) {
                    const int dg = col0 - 256, hh = dg >> 6, d0 = dg & 63;
                    const int unit = ((pos & 63) >> 4) * 2 + (d0 >> 5);
                    const int lt = ((d0 >> 3) & 3) * 16 + (pos & 15);
                    uint2 pp = {cvtpk(v0, v1), cvtpk(v2, v3)};
                    *(uint2*)&KVt[(((size_t)(eb * 4 + hh) * 2 + 0) * KT + ktile) * 4096
                                  + unit * 512 + lt * 8 + (d0 & 7)] = pp;
                }
            } else {
                if (ktile < KT) {
                    const int dg = col0 - 512, hh = dg >> 6, d0 = dg & 63;
                    const size_t vb = (((size_t)(eb * 4 + hh) * 2 + 1) * KT + ktile) * 4096
                                    + ((d0 >> 4) * 2 + ((pos & 63) >> 5)) * 512
                                    + ((((pos & 63) >> 3) & 3) * 16) * 8 + (pos & 7);
                    KVt[vb + (size_t)((d0 & 15) + 0) * 8] = f2bf(v0);
                    KVt[vb + (size_t)((d0 & 15) + 1) * 8] = f2bf(v1);
                    KVt[vb + (size_t)((d0 & 15) + 2) * 8] = f2bf(v2);
                    KVt[vb + (size_t)((d0 & 15) + 3) * 8] = f2bf(v3);
                }
            }
        }
    }
}

// ---------------- packed GEMM + residual + LN: 64 rows x 256 cols, 256 thr ----------------

__global__ __launch_bounds__(256) void mgemmln_kernel(const u16* __restrict__ Xp,
                                                      const u16* __restrict__ Wp,
                                                      const float* __restrict__ bias,
                                                      float* __restrict__ H,
                                                      const float* __restrict__ lnw,
                                                      const float* __restrict__ lnb,
                                                      u16* __restrict__ Yp,
                                                      int nkt) {
    __shared__ float part[2][4][64];
    const int m0 = blockIdx.x * 64;
    const int tid = threadIdx.x, wv = tid >> 6, lane = tid & 63;
    const int lhi = lane >> 4, llo = lane & 15;
    const int rt0 = m0 >> 4;

    f32x4 acc[4][4];
    #pragma unroll
    for (int i = 0; i < 4; ++i)
        #pragma unroll
        for (int j = 0; j < 4; ++j) acc[i][j] = (f32x4){0.f, 0.f, 0.f, 0.f};

    for (int kt = 0; kt < nkt; ++kt) {
        #pragma unroll
        for (int kk = 0; kk < 2; ++kk) {
            bf16x8 xf[4], wf[4];
            #pragma unroll
            for (int i = 0; i < 4; ++i)
                xf[i] = *(const bf16x8*)(Xp + ((size_t)(rt0 + i) * nkt + kt) * 1024
                                         + kk * 512 + lane * 8);
            #pragma unroll
            for (int j = 0; j < 4; ++j) {
                const int c16 = wv * 4 + j;
                wf[j] = *(const bf16x8*)(Wp + ((size_t)c16 * nkt + kt) * 1024
                                         + kk * 512 + lane * 8);
            }
            #pragma unroll
            for (int i = 0; i < 4; ++i)
                #pragma unroll
                for (int j = 0; j < 4; ++j)
                    acc[i][j] = __builtin_amdgcn_mfma_f32_16x16x32_bf16(wf[j], xf[i], acc[i][j], 0, 0, 0);
        }
    }

    float rsum[4], rsq[4];
    #pragma unroll
    for (int i = 0; i < 4; ++i) { rsum[i] = 0.f; rsq[i] = 0.f; }
    #pragma unroll
    for (int i = 0; i < 4; ++i) {
        const int row = m0 + i * 16 + llo;
        #pragma unroll
        for (int j = 0; j < 4; ++j) {
            const int col0 = wv * 64 + j * 16 + lhi * 4;
            const float4 bb = *(const float4*)&bias[col0];
            const float4 hv = *(const float4*)&H[(size_t)row * DM + col0];
            float v0 = acc[i][j][0] + bb.x + hv.x;
            float v1 = acc[i][j][1] + bb.y + hv.y;
            float v2 = acc[i][j][2] + bb.z + hv.z;
            float v3 = acc[i][j][3] + bb.w + hv.w;
            acc[i][j][0] = v0; acc[i][j][1] = v1; acc[i][j][2] = v2; acc[i][j][3] = v3;
            rsum[i] += (v0 + v1) + (v2 + v3);
            rsq[i]  += (v0 * v0 + v1 * v1) + (v2 * v2 + v3 * v3);
        }
    }
    #pragma unroll
    for (int i = 0; i < 4; ++i) {
        rsum[i] += __shfl_xor(rsum[i], 16);  rsum[i] += __shfl_xor(rsum[i], 32);
        rsq[i]  += __shfl_xor(rsq[i], 16);   rsq[i]  += __shfl_xor(rsq[i], 32);
    }
    __syncthreads();
    if (lhi == 0) {
        #pragma unroll
        for (int i = 0; i < 4; ++i) {
            const int rl = i * 16 + llo;
            part[0][wv][rl] = rsum[i];
            part[1][wv][rl] = rsq[i];
        }
    }
    __syncthreads();

    #pragma unroll
    for (int i = 0; i < 4; ++i) {
        const int rl = i * 16 + llo;
        const int row = m0 + rl;
        const float s = (part[0][0][rl] + part[0][1][rl]) + (part[0][2][rl] + part[0][3][rl]);
        const float q = (part[1][0][rl] + part[1][1][rl]) + (part[1][2][rl] + part[1][3][rl]);
        const float mean = s * (1.0f / 256.0f);
        const float var  = fmaxf(q * (1.0f / 256.0f) - mean * mean, 0.f);
        const float rstd = rsqrtf(var + LNEPS);
        #pragma unroll
        for (int j = 0; j < 4; ++j) {
            const int col0 = wv * 64 + j * 16 + lhi * 4;
            const float4 wl = *(const float4*)&lnw[col0];
            const float4 bl = *(const float4*)&lnb[col0];
            float4 hv;
            hv.x = acc[i][j][0]; hv.y = acc[i][j][1];
            hv.z = acc[i][j][2]; hv.w = acc[i][j][3];
            *(float4*)&H[(size_t)row * DM + col0] = hv;
            uint2 yy;
            yy.x = cvtpk((hv.x - mean) * rstd * wl.x + bl.x,
                         (hv.y - mean) * rstd * wl.y + bl.y);
            yy.y = cvtpk((hv.z - mean) * rstd * wl.z + bl.z,
                         (hv.w - mean) * rstd * wl.w + bl.w);
            *(uint2*)&Yp[apack(row, col0, 4)] = yy;
        }
    }
}

// ---------------- barrier-free fragment-packed flash attention ----------------
// 8 independent waves x 16 q = 128 q/block (512 thr); per-wave state identical
// to round 21 (VGPR ~64); zero __syncthreads; per-wave P LDS; fexp2 softmax.

__global__ __launch_bounds__(512) void mattn_kernel(const u16* __restrict__ Qb,
                                                    const u16* __restrict__ KVt,
                                                    const int* __restrict__ counts,
                                                    const int* __restrict__ starts,
                                                    u16* __restrict__ outp, int N) {
    const int id  = blockIdx.x;
    const int rem = id >> 3;
    const int qt  = rem % QTQ;
    const int bh  = (rem / QTQ) * 8 + (id & 7);
    const int b = bh >> 2, hh = bh & 3;
    const int Sb = counts[b] + 1;
    const int qbase = qt * 128;
    if (qbase >= Sb) return;
    const int start = starts[b];
    __shared__ u16 Pl[8][16 * 72];
    const int tid = threadIdx.x;
    const int w = tid >> 6, lane = tid & 63;
    const int llo = lane & 15, lhi = lane >> 4;

    const int qi = qbase + w * 16 + llo;
    const size_t qrow = (qi < Sb && qi > 0) ? (size_t)(start + qi - 1) : (size_t)(N + b);
    bf16x8 bq[2];
    bq[0] = *(const bf16x8*)(Qb + qrow * 256 + hh * 64 + lhi * 8);
    bq[1] = *(const bf16x8*)(Qb + qrow * 256 + hh * 64 + 32 + lhi * 8);

    const u16* kb = KVt + ((size_t)bh * 2 + 0) * KT * 4096;
    const u16* vb = KVt + ((size_t)bh * 2 + 1) * KT * 4096;

    f32x4 acc[4];
    #pragma unroll
    for (int i = 0; i < 4; ++i) acc[i] = (f32x4){0.f, 0.f, 0.f, 0.f};
    float m = -1e30f, l = 0.f;

    int nt = (Sb + 63) >> 6;
    if (nt > KT) nt = KT;

    for (int t = 0; t < nt; ++t) {
        const int kbase = t * 64;
        const u16* kp = kb + t * 4096 + lane * 8;
        const u16* vp = vb + t * 4096 + lane * 8;

        bf16x8 ak[4][2], av[4][2];
        #pragma unroll
        for (int i = 0; i < 4; ++i) {
            #pragma unroll
            for (int kk = 0; kk < 2; ++kk) {
                ak[i][kk] = *(const bf16x8*)(kp + (i * 2 + kk) * 512);
                av[i][kk] = *(const bf16x8*)(vp + (i * 2 + kk) * 512);
            }
        }

        f32x4 sc[4];
        #pragma unroll
        for (int i = 0; i < 4; ++i) sc[i] = (f32x4){0.f, 0.f, 0.f, 0.f};
        __builtin_amdgcn_s_setprio(1);
        #pragma unroll
        for (int kk = 0; kk < 2; ++kk)
            #pragma unroll
            for (int i = 0; i < 4; ++i)
                sc[i] = __builtin_amdgcn_mfma_f32_16x16x32_bf16(ak[i][kk], bq[kk], sc[i], 0, 0, 0);
        __builtin_amdgcn_s_setprio(0);

        float rm;
        if (kbase + 64 <= Sb) {
            float m0v = fmaxf(fmaxf(sc[0][0], sc[0][1]), fmaxf(sc[0][2], sc[0][3]));
            float m1v = fmaxf(fmaxf(sc[1][0], sc[1][1]), fmaxf(sc[1][2], sc[1][3]));
            float m2v = fmaxf(fmaxf(sc[2][0], sc[2][1]), fmaxf(sc[2][2], sc[2][3]));
            float m3v = fmaxf(fmaxf(sc[3][0], sc[3][1]), fmaxf(sc[3][2], sc[3][3]));
            rm = fmaxf(fmaxf(m0v, m1v), fmaxf(m2v, m3v));
        } else {
            rm = -1e30f;
            #pragma unroll
            for (int i = 0; i < 4; ++i)
                #pragma unroll
                for (int r = 0; r < 4; ++r) {
                    const int key = kbase + i * 16 + lhi * 4 + r;
                    const float s = (key < Sb) ? sc[i][r] : -1e30f;
                    sc[i][r] = s;
                    rm = fmaxf(rm, s);
                }
        }
        rm = fmaxf(rm, __shfl_xor(rm, 16));
        rm = fmaxf(rm, __shfl_xor(rm, 32));

        if (!__all(rm <= m + 8.f)) {
            const float mnew = fmaxf(m, rm);
            const float corr = fexp2(m - mnew);
            l *= corr;
            #pragma unroll
            for (int i = 0; i < 4; ++i) acc[i] *= corr;
            m = mnew;
        }

        float ls = 0.f;
        #pragma unroll
        for (int i = 0; i < 4; ++i) {
            const float p0 = fexp2(sc[i][0] - m), p1 = fexp2(sc[i][1] - m);
            const float p2 = fexp2(sc[i][2] - m), p3 = fexp2(sc[i][3] - m);
            ls += (p0 + p1) + (p2 + p3);
            uint2 pp;
            pp.x = cvtpk(p0, p1);
            pp.y = cvtpk(p2, p3);
            *(uint2*)&Pl[w][llo * 72 + i * 16 + lhi * 4] = pp;
        }
        ls += __shfl_xor(ls, 16);
        ls += __shfl_xor(ls, 32);
        l += ls;

        __builtin_amdgcn_s_setprio(1);
        #pragma unroll
        for (int kk = 0; kk < 2; ++kk) {
            bf16x8 pb = *(const bf16x8*)&Pl[w][llo * 72 + kk * 32 + lhi * 8];
            #pragma unroll
            for (int i = 0; i < 4; ++i)
                acc[i] = __builtin_amdgcn_mfma_f32_16x16x32_bf16(av[i][kk], pb, acc[i], 0, 0, 0);
        }
        __builtin_amdgcn_s_setprio(0);
    }

    if (qi < Sb) {
        const size_t orow = (qi == 0) ? (size_t)(N + b) : (size_t)(start + qi - 1);
        const float invl = 1.f / l;
        #pragma unroll
        for (int i = 0; i < 4; ++i) {
            const int col0 = hh * 64 + i * 16 + lhi * 4;
            uint2 yy;
            yy.x = cvtpk(acc[i][0] * invl, acc[i][1] * invl);
            yy.y = cvtpk(acc[i][2] * invl, acc[i][3] * invl);
            *(uint2*)&outp[apack((int)orow, col0, 4)] = yy;
        }
    }
}

// ---------------- head ----------------

__global__ __launch_bounds__(256) void head_kernel(const float* __restrict__ h,
                                                   const float* __restrict__ w1,
                                                   const float* __restrict__ b1,
                                                   const float* __restrict__ w2,
                                                   const float* __restrict__ b2,
                                                   float* __restrict__ out, int N) {
    const int b = blockIdx.x;
    const int t = threadIdx.x;
    __shared__ float cls[DM];
    __shared__ float hid[DM];
    cls[t] = h[(size_t)(N + b) * DM + t];
    __syncthreads();
    float s = b1[t];
    for (int k = 0; k < DM; ++k) s = fmaf(cls[k], w1[t * DM + k], s);
    hid[t] = fmaxf(s, 0.f);
    __syncthreads();
    if (t < 2) {
        float o = b2[t];
        for (int k = 0; k < DM; ++k) o = fmaf(hid[k], w2[t * DM + k], o);
        out[b * 2 + t] = o;
    }
}

// ---------------- launch ----------------

extern "C" void kernel_launch(void* const* d_in, const int* in_sizes, int n_in,
                              void* d_out, int out_size, void* d_ws, size_t ws_size,
                              hipStream_t stream) {
    const float* dom_emb   = (const float*)d_in[0];
    const int*   dom_idx   = (const int*)d_in[1];
    const float* geometry  = (const float*)d_in[3];
    const float* in_w      = (const float*)d_in[4];
    const float* in_b      = (const float*)d_in[5];
    const float* geo_w     = (const float*)d_in[6];
    const float* geo_b     = (const float*)d_in[7];
    const float* cls_tok   = (const float*)d_in[8];
    const float* qkv_w     = (const float*)d_in[9];
    const float* qkv_b     = (const float*)d_in[10];
    const float* out_w     = (const float*)d_in[11];
    const float* out_b     = (const float*)d_in[12];
    const float* ln1_w     = (const float*)d_in[13];
    const float* ln1_b     = (const float*)d_in[14];
    const float* ln2_w     = (const float*)d_in[15];
    const float* ln2_b     = (const float*)d_in[16];
    const float* ff_w1     = (const float*)d_in[17];
    const float* ff_b1     = (const float*)d_in[18];
    const float* ff_w2     = (const float*)d_in[19];
    const float* ff_b2     = (const float*)d_in[20];
    const float* head_w1   = (const float*)d_in[21];
    const float* head_b1   = (const float*)d_in[22];
    const float* head_w2   = (const float*)d_in[23];
    const float* head_b2   = (const float*)d_in[24];
    float* outp = (float*)d_out;

    const int N  = in_sizes[0] / D_INPUT;      // 65536
    const int T  = N + BEV;                    // 65664
    const int TP = ((T + 255) / 256) * 256;    // 65792 = 1028*64

    // workspace layout (bytes)
    char* base = (char*)d_ws;
    size_t off = 0;
    int* counts = (int*)(base + off);          off += 1024;
    int* starts = (int*)(base + off);          off += 1024;
    u16*   Web  = (u16*)(base + off);          off += (size_t)256 * 384 * 2;
    float* be   = (float*)(base + off);        off += 1024;
    u16*   wq   = (u16*)(base + off);          off += (size_t)NLAYERS * 768 * 256 * 2;
    u16*   wo   = (u16*)(base + off);          off += (size_t)NLAYERS * 256 * 256 * 2;
    u16*   w1b  = (u16*)(base + off);          off += (size_t)NLAYERS * 1024 * 256 * 2;
    u16*   w2b  = (u16*)(base + off);          off += (size_t)NLAYERS * 256 * 1024 * 2;
    int*   r2bs = (int*)(base + off);          off += ((size_t)TP * 4 + 255) & ~255ULL;
    float* h    = (float*)(base + off);        off += (size_t)TP * DM * 4;    // 67.4 MB
    u16*   xb   = (u16*)(base + off);          off += (size_t)TP * DM * 2;    // 33.7 MB (packed)
    const size_t qb_sz  = (size_t)TP * 256 * 2;                          // 33.7 MB
    const size_t kvt_sz = (size_t)(BEV + 1) * 4 * 2 * KT * 4096 * 2;     // 84.6 MB
    const size_t big2   = qb_sz + kvt_sz;                                // 118.3 MB
    const size_t ffm_sz = (size_t)TP * 1024 * 2;                         // 134.7 MB (full)
    char* bigc = base + off;
    // runtime choice: single-chunk FF if workspace allows (deterministic per run)
    const bool ff_single = ws_size >= off + (ffm_sz > big2 ? ffm_sz : big2);
    off += ff_single ? (ffm_sz > big2 ? ffm_sz : big2) : big2;

    u16* Ab   = (u16*)bigc;                    // packed embed A (prep phase only)
    u16* Qbuf = (u16*)bigc;
    u16* KVt  = (u16*)(bigc + qb_sz);
    u16* ffm  = (u16*)bigc;                    // packed FF mid (full or TP/2 chunk)

    if (ws_size < off) {
        beacon_kernel<<<1, 256, 0, stream>>>(outp, out_size, (float)(ws_size >> 20));
        return;
    }

    // ---- weights: bf16 + fragment packing ----
    {
        const int ntot = NLAYERS * (768 * 256 + 256 * 256 + 1024 * 256 + 256 * 1024);
        cvt4p_kernel<<<(ntot + 255) / 256, 256, 0, stream>>>(
            qkv_w, out_w, ff_w1, ff_w2, wq, wo, w1b, w2b);
    }
    prep_w_kernel<<<(256 * 384 + 255) / 256, 256, 0, stream>>>(in_w, geo_w, in_b, geo_b, Web, be);

    // ---- event bookkeeping ----
    starts_kernel<<<1, 256, 0, stream>>>(dom_idx, counts, starts, N);
    r2bs_kernel<<<(TP + 255) / 256, 256, 0, stream>>>(dom_idx, starts, r2bs, N, TP);

    // ---- embed ----
    prep_a_kernel<<<(int)(((size_t)N * 96 + 255) / 256), 256, 0, stream>>>(dom_emb, geometry, Ab, N);
    pgemm_kernel<0><<<dim3(1, N / 64), 256, 0, stream>>>(
        Ab, Web, be, h, nullptr, nullptr, nullptr, 6);
    cls_kernel<<<BEV, DM, 0, stream>>>(cls_tok, h, N);

    // ---- transformer layers ----
    ln_kernel<<<TP / 4, 256, 0, stream>>>(h, ln1_w, ln1_b, xb, TP);
    for (int l = 0; l < NLAYERS; ++l) {
        pgemm_kernel<1><<<dim3(3, TP / 64), 256, 0, stream>>>(
            xb, wq + (size_t)l * 768 * 256, qkv_b + l * 768, nullptr, Qbuf, KVt, r2bs, 4);
        mattn_kernel<<<8 * QTQ * (BEV * NHEADS / 8), 512, 0, stream>>>(
            Qbuf, KVt, counts, starts, xb, N);
        mgemmln_kernel<<<TP / 64, 256, 0, stream>>>(
            xb, wo + (size_t)l * 256 * 256, out_b + l * DM, h,
            ln2_w + l * DM, ln2_b + l * DM, xb, 4);
        const int lnx = (l + 1 < NLAYERS) ? (l + 1) : l;   // dummy LN for last layer
        if (ff_single) {
            pgemm_kernel<2><<<dim3(4, TP / 64), 256, 0, stream>>>(
                xb, w1b + (size_t)l * DFF * 256, ff_b1 + l * DFF, nullptr, ffm,
                nullptr, nullptr, 4);
            mgemmln_kernel<<<TP / 64, 256, 0, stream>>>(
                ffm, w2b + (size_t)l * 256 * DFF, ff_b2 + l * DM, h,
                ln1_w + lnx * DM, ln1_b + lnx * DM, xb, 16);
        } else {
            for (int c = 0; c < 2; ++c) {
                const int r0 = c * (TP / 2);
                const u16* xc = xb + ((size_t)(r0 >> 4)) * 4 * 1024;
                pgemm_kernel<2><<<dim3(4, TP / 128), 256, 0, stream>>>(
                    xc, w1b + (size_t)l * DFF * 256, ff_b1 + l * DFF, nullptr, ffm,
                    nullptr, nullptr, 4);
                mgemmln_kernel<<<TP / 128, 256, 0, stream>>>(
                    ffm, w2b + (size_t)l * 256 * DFF, ff_b2 + l * DM, h + (size_t)r0 * DM,
                    ln1_w + lnx * DM, ln1_b + lnx * DM,
                    xb + ((size_t)(r0 >> 4)) * 4 * 1024, 16);
            }
        }
    }

    // ---- head ----
    head_kernel<<<BEV, DM, 0, stream>>>(h, head_w1, head_b1, head_w2, head_b2, outp, N);
}

// Round 23
// 1570.328 us; speedup vs baseline: 1.0119x; 1.0119x over previous
//
#include <hip/hip_runtime.h>
#include <hip/hip_bf16.h>
#include <math.h>

// EventTransformer on MI355X — FINAL (round-21 config, best: 1573us).
// Fully fragment-packed dataflow: all activations and weights stored in
// MFMA-fragment order in global memory; every GEMM reads coalesced 1KB
// fragments directly (no LDS staging, no barriers in GEMM k-loops).
// Attention: barrier-free, 4 independent waves/block, fragment-packed K/V
// (written by the qkv GEMM epilogue), swapped-operand QK^T with in-register
// softmax (exp2 domain via pre-scaled Q, native v_exp_f32, defer-max THR=8),
// XCD-grouped grid for K/V L2 residency. LN fused into out-proj/ff2 epilogues.
// Single-chunk FF when workspace permits (runtime-deterministic).

#define D_INPUT  128
#define DM       256
#define NHEADS   4
#define HDIM     64
#define NLAYERS  4
#define DFF      1024
#define BEV      128
#define LNEPS    1e-5f
#define KT       10      // key tiles of 64 per (b,h): covers Sb <= 640
#define SCL      0.18033688011112042f   // 0.125 * log2(e)

typedef unsigned short u16;
typedef __attribute__((ext_vector_type(8))) short bf16x8;
typedef __attribute__((ext_vector_type(4))) float f32x4;

__device__ inline u16 f2bf(float x) {
    unsigned int xi = __float_as_uint(x);
    unsigned int r  = xi + 0x7FFFu + ((xi >> 16) & 1u);   // RNE
    return (u16)(r >> 16);
}
__device__ inline unsigned int cvtpk(float lo, float hi) {
    unsigned int r;
    asm("v_cvt_pk_bf16_f32 %0, %1, %2" : "=v"(r) : "v"(lo), "v"(hi));
    return r;
}
__device__ inline float fexp2(float x) { return __builtin_amdgcn_exp2f(x); }

// Packed-activation element offset (u16 units). Matrix (rows x K), nkt=K/64.
// Fragment read: base + ((row>>4)*nkt + kt)*1024 + kk*512 + lane*8.
__device__ inline size_t apack(int row, int col, int nkt) {
    return ((size_t)(row >> 4) * nkt + (col >> 6)) * 1024
         + ((col >> 5) & 1) * 512
         + ((((col >> 3) & 3) * 16 + (row & 15)) * 8) + (col & 7);
}
// Packed-weight offset (identical formula; col = output col, row = k).
__device__ inline size_t wpack_off(int col, int k, int nkt) {
    const int c16 = col >> 4, llo = col & 15;
    const int kt = k >> 6, kr = k & 63;
    const int kk = kr >> 5, lhi = (kr >> 3) & 3, e = kr & 7;
    return ((size_t)(c16 * nkt + kt)) * 1024 + kk * 512 + (lhi * 16 + llo) * 8 + e;
}

// ---------------- prep kernels ----------------

__global__ void starts_kernel(const int* __restrict__ idx, int* __restrict__ counts,
                              int* __restrict__ starts, int N) {
    __shared__ int bnd[BEV + 1];
    const int b = threadIdx.x;
    if (b <= BEV) {
        int lo = 0, hi = N;
        while (lo < hi) { int mid = (lo + hi) >> 1; if (idx[mid] < b) lo = mid + 1; else hi = mid; }
        bnd[b] = lo;
    }
    __syncthreads();
    if (b < BEV) { starts[b] = bnd[b]; counts[b] = bnd[b + 1] - bnd[b]; }
}

__global__ void r2bs_kernel(const int* __restrict__ idx, const int* __restrict__ starts,
                            int* __restrict__ r2bs, int N, int TP) {
    int i = blockIdx.x * blockDim.x + threadIdx.x;
    if (i < N) {
        int b = idx[i];
        r2bs[i] = (b << 16) | (i - starts[b] + 1);
    } else if (i < N + BEV) {
        r2bs[i] = (i - N) << 16;
    } else if (i < TP) {
        r2bs[i] = BEV << 16;
    }
}

__global__ void beacon_kernel(float* out, int n, float v) {
    int i = blockIdx.x * blockDim.x + threadIdx.x;
    if (i < n) out[i] = v;
}

// fp32 -> bf16 + fragment packing of all 4 weight groups
__global__ void cvt4p_kernel(const float* __restrict__ s0, const float* __restrict__ s1,
                             const float* __restrict__ s2, const float* __restrict__ s3,
                             u16* __restrict__ d0, u16* __restrict__ d1,
                             u16* __restrict__ d2, u16* __restrict__ d3) {
    const int n0 = NLAYERS * 768 * 256, n1 = NLAYERS * 256 * 256;
    const int n2 = NLAYERS * 1024 * 256, n3 = NLAYERS * 256 * 1024;
    int i = blockIdx.x * blockDim.x + threadIdx.x;
    if (i < n0) {
        const int NoK = 768 * 256;
        int l = i / NoK, rem = i - l * NoK, col = rem >> 8, k = rem & 255;
        d0[(size_t)l * NoK + wpack_off(col, k, 4)] = f2bf(s0[i]);
        return;
    }
    i -= n0;
    if (i < n1) {
        const int NoK = 256 * 256;
        int l = i / NoK, rem = i - l * NoK, col = rem >> 8, k = rem & 255;
        d1[(size_t)l * NoK + wpack_off(col, k, 4)] = f2bf(s1[i]);
        return;
    }
    i -= n1;
    if (i < n2) {
        const int NoK = 1024 * 256;
        int l = i / NoK, rem = i - l * NoK, col = rem >> 8, k = rem & 255;
        d2[(size_t)l * NoK + wpack_off(col, k, 4)] = f2bf(s2[i]);
        return;
    }
    i -= n2;
    if (i < n3) {
        const int NoK = 256 * 1024;
        int l = i / NoK, rem = i - l * NoK, col = rem >> 10, k = rem & 1023;
        d3[(size_t)l * NoK + wpack_off(col, k, 16)] = f2bf(s3[i]);
    }
}

// We (256 x 384) packed = [in_proj_w | geo_proj_w[:, :252] | 0]; be = in_b+geo_b
__global__ void prep_w_kernel(const float* __restrict__ win, const float* __restrict__ wgeo,
                              const float* __restrict__ bin, const float* __restrict__ bgeo,
                              u16* __restrict__ We, float* __restrict__ be) {
    int i = blockIdx.x * blockDim.x + threadIdx.x;
    if (i < 256 * 384) {
        int o = i / 384, k = i % 384;
        float v = 0.f;
        if (k < 128)      v = win[o * 128 + k];
        else if (k < 380) v = wgeo[o * 256 + (k - 128)];
        We[wpack_off(o, k, 6)] = f2bf(v);
    }
    if (i < 256) be[i] = bin[i] + bgeo[i];
}

// A (N x 384) PACKED bf16 = [dom_embeddings | pos_enc (252) | 0]; 4 cols/thread.
__global__ void prep_a_kernel(const float* __restrict__ emb, const float* __restrict__ geo,
                              u16* __restrict__ Ap, int N) {
    size_t t = (size_t)blockIdx.x * blockDim.x + threadIdx.x;
    if (t >= (size_t)N * 96) return;
    const int c4 = (int)(t % 96) * 4;
    const size_t r = t / 96;
    float v[4];
    #pragma unroll
    for (int u = 0; u < 4; ++u) {
        const int k = c4 + u;
        float x = 0.f;
        if (k < 128) {
            x = emb[r * 128 + k];
        } else if (k < 380) {
            int rem  = k - 128;
            int axis = rem / 84;
            int r2   = rem % 84;
            int band = r2 >> 1;
            int sc   = r2 & 1;
            float freq = expf((float)band * (2.3025850929940457f / 41.0f)); // 10^(band/41)
            float ang  = (6.283185307179586f * geo[r * 3 + axis]) * freq;
            x = sc ? cosf(ang) : sinf(ang);
        }
        v[u] = x;
    }
    uint2 pp;
    pp.x = cvtpk(v[0], v[1]);
    pp.y = cvtpk(v[2], v[3]);
    *(uint2*)&Ap[apack((int)r, c4, 6)] = pp;
}

__global__ void cls_kernel(const float* __restrict__ cls, float* __restrict__ h, int N) {
    h[(size_t)(N + blockIdx.x) * DM + threadIdx.x] = cls[threadIdx.x];
}

// ---------------- layernorm (layer-0 ln1 only), PACKED output ----------------

__global__ __launch_bounds__(256) void ln_kernel(const float* __restrict__ x,
                                                 const float* __restrict__ w,
                                                 const float* __restrict__ b,
                                                 u16* __restrict__ yp, int T) {
    int row  = blockIdx.x * 4 + (threadIdx.x >> 6);
    int lane = threadIdx.x & 63;
    if (row >= T) return;
    float4 v = ((const float4*)(x + (size_t)row * DM))[lane];
    float s = v.x + v.y + v.z + v.w;
    #pragma unroll
    for (int off = 32; off > 0; off >>= 1) s += __shfl_xor(s, off);
    float mean = s * (1.0f / 256.0f);
    float dx = v.x - mean, dy = v.y - mean, dz = v.z - mean, dw = v.w - mean;
    float ss = dx * dx + dy * dy + dz * dz + dw * dw;
    #pragma unroll
    for (int off = 32; off > 0; off >>= 1) ss += __shfl_xor(ss, off);
    float inv = rsqrtf(ss * (1.0f / 256.0f) + LNEPS);
    float4 wv = ((const float4*)w)[lane];
    float4 bv = ((const float4*)b)[lane];
    const int col0 = lane * 4;
    uint2 yy;
    yy.x = cvtpk(dx * inv * wv.x + bv.x, dy * inv * wv.y + bv.y);
    yy.y = cvtpk(dz * inv * wv.z + bv.z, dw * inv * wv.w + bv.w);
    *(uint2*)&yp[apack(row, col0, 4)] = yy;
}

// ---------------- barrier-free packed GEMM: 64 rows x 256 cols, 256 thr ----------------
// MODE 0: C = X@W^T + bias (f32 row-major, embed).
// MODE 1: qkv split (n0==0 -> Q row-major *SCL; 256 -> K tiled; 512 -> V tiled).
// MODE 2: ff1 -> relu, packed bf16 output (nkt_out=16) into Qb arg.

template <int MODE>
__global__ __launch_bounds__(256) void pgemm_kernel(const u16* __restrict__ Xp,
                                                    const u16* __restrict__ Wp,
                                                    const float* __restrict__ bias,
                                                    float* __restrict__ C,
                                                    u16* __restrict__ Qb,
                                                    u16* __restrict__ KVt,
                                                    const int* __restrict__ r2bs,
                                                    int nkt) {
    const int m0 = blockIdx.y * 64, n0 = blockIdx.x * 256;
    const int tid = threadIdx.x, wv = tid >> 6, lane = tid & 63;
    const int lhi = lane >> 4, llo = lane & 15;
    const int rt0 = m0 >> 4;

    f32x4 acc[4][4];
    #pragma unroll
    for (int i = 0; i < 4; ++i)
        #pragma unroll
        for (int j = 0; j < 4; ++j) acc[i][j] = (f32x4){0.f, 0.f, 0.f, 0.f};

    for (int kt = 0; kt < nkt; ++kt) {
        #pragma unroll
        for (int kk = 0; kk < 2; ++kk) {
            bf16x8 xf[4], wf[4];
            #pragma unroll
            for (int i = 0; i < 4; ++i)
                xf[i] = *(const bf16x8*)(Xp + ((size_t)(rt0 + i) * nkt + kt) * 1024
                                         + kk * 512 + lane * 8);
            #pragma unroll
            for (int j = 0; j < 4; ++j) {
                const int c16 = (n0 >> 4) + wv * 4 + j;
                wf[j] = *(const bf16x8*)(Wp + ((size_t)c16 * nkt + kt) * 1024
                                         + kk * 512 + lane * 8);
            }
            #pragma unroll
            for (int i = 0; i < 4; ++i)
                #pragma unroll
                for (int j = 0; j < 4; ++j)
                    acc[i][j] = __builtin_amdgcn_mfma_f32_16x16x32_bf16(wf[j], xf[i], acc[i][j], 0, 0, 0);
        }
    }

    #pragma unroll
    for (int i = 0; i < 4; ++i) {
        const int row = m0 + i * 16 + llo;
        int eb = 0, pos = 0, ktile = KT;
        if (MODE == 1 && n0 >= 256) {
            const int bs = r2bs[row];
            eb = bs >> 16; pos = bs & 0xffff; ktile = pos >> 6;
        }
        #pragma unroll
        for (int j = 0; j < 4; ++j) {
            const int col0 = n0 + wv * 64 + j * 16 + lhi * 4;
            const float4 bb = *(const float4*)&bias[col0];
            const float v0 = acc[i][j][0] + bb.x, v1 = acc[i][j][1] + bb.y;
            const float v2 = acc[i][j][2] + bb.z, v3 = acc[i][j][3] + bb.w;
            if (MODE == 0) {
                float4 c = {v0, v1, v2, v3};
                *(float4*)&C[(size_t)row * 256 + col0] = c;
            } else if (MODE == 2) {
                uint2 yy;
                yy.x = cvtpk(fmaxf(v0, 0.f), fmaxf(v1, 0.f));
                yy.y = cvtpk(fmaxf(v2, 0.f), fmaxf(v3, 0.f));
                *(uint2*)&Qb[apack(row, col0, 16)] = yy;
            } else if (n0 == 0) {
                uint2 q;
                q.x = cvtpk(v0 * SCL, v1 * SCL);
                q.y = cvtpk(v2 * SCL, v3 * SCL);
                *(uint2*)&Qb[(size_t)row * 256 + col0] = q;
            } else if (n0 == 256) {
                if (ktile < KT) {
                    const int dg = col0 - 256, hh = dg >> 6, d0 = dg & 63;
                    const int unit = ((pos & 63) >> 4) * 2 + (d0 >> 5);
                    const int lt = ((d0 >> 3) & 3) * 16 + (pos & 15);
                    uint2 pp = {cvtpk(v0, v1), cvtpk(v2, v3)};
                    *(uint2*)&KVt[(((size_t)(eb * 4 + hh) * 2 + 0) * KT + ktile) * 4096
                                  + unit * 512 + lt * 8 + (d0 & 7)] = pp;
                }
            } else {
                if (ktile < KT) {
                    const int dg = col0 - 512, hh = dg >> 6, d0 = dg & 63;
                    const size_t vb = (((size_t)(eb * 4 + hh) * 2 + 1) * KT + ktile) * 4096
                                    + ((d0 >> 4) * 2 + ((pos & 63) >> 5)) * 512
                                    + ((((pos & 63) >> 3) & 3) * 16) * 8 + (pos & 7);
                    KVt[vb + (size_t)((d0 & 15) + 0) * 8] = f2bf(v0);
                    KVt[vb + (size_t)((d0 & 15) + 1) * 8] = f2bf(v1);
                    KVt[vb + (size_t)((d0 & 15) + 2) * 8] = f2bf(v2);
                    KVt[vb + (size_t)((d0 & 15) + 3) * 8] = f2bf(v3);
                }
            }
        }
    }
}

// ---------------- packed GEMM + residual + LN: 64 rows x 256 cols, 256 thr ----------------

__global__ __launch_bounds__(256) void mgemmln_kernel(const u16* __restrict__ Xp,
                                                      const u16* __restrict__ Wp,
                                                      const float* __restrict__ bias,
                                                      float* __restrict__ H,
                                                      const float* __restrict__ lnw,
                                                      const float* __restrict__ lnb,
                                                      u16* __restrict__ Yp,
                                                      int nkt) {
    __shared__ float part[2][4][64];
    const int m0 = blockIdx.x * 64;
    const int tid = threadIdx.x, wv = tid >> 6, lane = tid & 63;
    const int lhi = lane >> 4, llo = lane & 15;
    const int rt0 = m0 >> 4;

    f32x4 acc[4][4];
    #pragma unroll
    for (int i = 0; i < 4; ++i)
        #pragma unroll
        for (int j = 0; j < 4; ++j) acc[i][j] = (f32x4){0.f, 0.f, 0.f, 0.f};

    for (int kt = 0; kt < nkt; ++kt) {
        #pragma unroll
        for (int kk = 0; kk < 2; ++kk) {
            bf16x8 xf[4], wf[4];
            #pragma unroll
            for (int i = 0; i < 4; ++i)
                xf[i] = *(const bf16x8*)(Xp + ((size_t)(rt0 + i) * nkt + kt) * 1024
                                         + kk * 512 + lane * 8);
            #pragma unroll
            for (int j = 0; j < 4; ++j) {
                const int c16 = wv * 4 + j;
                wf[j] = *(const bf16x8*)(Wp + ((size_t)c16 * nkt + kt) * 1024
                                         + kk * 512 + lane * 8);
            }
            #pragma unroll
            for (int i = 0; i < 4; ++i)
                #pragma unroll
                for (int j = 0; j < 4; ++j)
                    acc[i][j] = __builtin_amdgcn_mfma_f32_16x16x32_bf16(wf[j], xf[i], acc[i][j], 0, 0, 0);
        }
    }

    float rsum[4], rsq[4];
    #pragma unroll
    for (int i = 0; i < 4; ++i) { rsum[i] = 0.f; rsq[i] = 0.f; }
    #pragma unroll
    for (int i = 0; i < 4; ++i) {
        const int row = m0 + i * 16 + llo;
        #pragma unroll
        for (int j = 0; j < 4; ++j) {
            const int col0 = wv * 64 + j * 16 + lhi * 4;
            const float4 bb = *(const float4*)&bias[col0];
            const float4 hv = *(const float4*)&H[(size_t)row * DM + col0];
            float v0 = acc[i][j][0] + bb.x + hv.x;
            float v1 = acc[i][j][1] + bb.y + hv.y;
            float v2 = acc[i][j][2] + bb.z + hv.z;
            float v3 = acc[i][j][3] + bb.w + hv.w;
            acc[i][j][0] = v0; acc[i][j][1] = v1; acc[i][j][2] = v2; acc[i][j][3] = v3;
            rsum[i] += (v0 + v1) + (v2 + v3);
            rsq[i]  += (v0 * v0 + v1 * v1) + (v2 * v2 + v3 * v3);
        }
    }
    #pragma unroll
    for (int i = 0; i < 4; ++i) {
        rsum[i] += __shfl_xor(rsum[i], 16);  rsum[i] += __shfl_xor(rsum[i], 32);
        rsq[i]  += __shfl_xor(rsq[i], 16);   rsq[i]  += __shfl_xor(rsq[i], 32);
    }
    __syncthreads();
    if (lhi == 0) {
        #pragma unroll
        for (int i = 0; i < 4; ++i) {
            const int rl = i * 16 + llo;
            part[0][wv][rl] = rsum[i];
            part[1][wv][rl] = rsq[i];
        }
    }
    __syncthreads();

    #pragma unroll
    for (int i = 0; i < 4; ++i) {
        const int rl = i * 16 + llo;
        const int row = m0 + rl;
        const float s = (part[0][0][rl] + part[0][1][rl]) + (part[0][2][rl] + part[0][3][rl]);
        const float q = (part[1][0][rl] + part[1][1][rl]) + (part[1][2][rl] + part[1][3][rl]);
        const float mean = s * (1.0f / 256.0f);
        const float var  = fmaxf(q * (1.0f / 256.0f) - mean * mean, 0.f);
        const float rstd = rsqrtf(var + LNEPS);
        #pragma unroll
        for (int j = 0; j < 4; ++j) {
            const int col0 = wv * 64 + j * 16 + lhi * 4;
            const float4 wl = *(const float4*)&lnw[col0];
            const float4 bl = *(const float4*)&lnb[col0];
            float4 hv;
            hv.x = acc[i][j][0]; hv.y = acc[i][j][1];
            hv.z = acc[i][j][2]; hv.w = acc[i][j][3];
            *(float4*)&H[(size_t)row * DM + col0] = hv;
            uint2 yy;
            yy.x = cvtpk((hv.x - mean) * rstd * wl.x + bl.x,
                         (hv.y - mean) * rstd * wl.y + bl.y);
            yy.y = cvtpk((hv.z - mean) * rstd * wl.z + bl.z,
                         (hv.w - mean) * rstd * wl.w + bl.w);
            *(uint2*)&Yp[apack(row, col0, 4)] = yy;
        }
    }
}

// ---------------- barrier-free fragment-packed flash attention (QF=1 + fexp2) ----------------

__global__ __launch_bounds__(256) void mattn_kernel(const u16* __restrict__ Qb,
                                                    const u16* __restrict__ KVt,
                                                    const int* __restrict__ counts,
                                                    const int* __restrict__ starts,
                                                    u16* __restrict__ outp, int N) {
    const int id  = blockIdx.x;
    const int rem = id >> 3;
    const int qt  = rem % KT;
    const int bh  = (rem / KT) * 8 + (id & 7);
    const int b = bh >> 2, hh = bh & 3;
    const int Sb = counts[b] + 1;
    const int qbase = qt * 64;
    if (qbase >= Sb) return;
    const int start = starts[b];
    __shared__ u16 Pl[4][16 * 72];
    const int tid = threadIdx.x;
    const int w = tid >> 6, lane = tid & 63;
    const int llo = lane & 15, lhi = lane >> 4;

    const int qi = qbase + w * 16 + llo;
    const size_t qrow = (qi < Sb && qi > 0) ? (size_t)(start + qi - 1) : (size_t)(N + b);
    bf16x8 bq[2];
    bq[0] = *(const bf16x8*)(Qb + qrow * 256 + hh * 64 + lhi * 8);
    bq[1] = *(const bf16x8*)(Qb + qrow * 256 + hh * 64 + 32 + lhi * 8);

    const u16* kb = KVt + ((size_t)bh * 2 + 0) * KT * 4096;
    const u16* vb = KVt + ((size_t)bh * 2 + 1) * KT * 4096;

    f32x4 acc[4];
    #pragma unroll
    for (int i = 0; i < 4; ++i) acc[i] = (f32x4){0.f, 0.f, 0.f, 0.f};
    float m = -1e30f, l = 0.f;

    int nt = (Sb + 63) >> 6;
    if (nt > KT) nt = KT;

    for (int t = 0; t < nt; ++t) {
        const int kbase = t * 64;
        const u16* kp = kb + t * 4096 + lane * 8;
        const u16* vp = vb + t * 4096 + lane * 8;

        bf16x8 ak[4][2], av[4][2];
        #pragma unroll
        for (int i = 0; i < 4; ++i) {
            #pragma unroll
            for (int kk = 0; kk < 2; ++kk) {
                ak[i][kk] = *(const bf16x8*)(kp + (i * 2 + kk) * 512);
                av[i][kk] = *(const bf16x8*)(vp + (i * 2 + kk) * 512);
            }
        }

        f32x4 sc[4];
        #pragma unroll
        for (int i = 0; i < 4; ++i) sc[i] = (f32x4){0.f, 0.f, 0.f, 0.f};
        __builtin_amdgcn_s_setprio(1);
        #pragma unroll
        for (int kk = 0; kk < 2; ++kk)
            #pragma unroll
            for (int i = 0; i < 4; ++i)
                sc[i] = __builtin_amdgcn_mfma_f32_16x16x32_bf16(ak[i][kk], bq[kk], sc[i], 0, 0, 0);
        __builtin_amdgcn_s_setprio(0);

        float rm;
        if (kbase + 64 <= Sb) {
            float m0v = fmaxf(fmaxf(sc[0][0], sc[0][1]), fmaxf(sc[0][2], sc[0][3]));
            float m1v = fmaxf(fmaxf(sc[1][0], sc[1][1]), fmaxf(sc[1][2], sc[1][3]));
            float m2v = fmaxf(fmaxf(sc[2][0], sc[2][1]), fmaxf(sc[2][2], sc[2][3]));
            float m3v = fmaxf(fmaxf(sc[3][0], sc[3][1]), fmaxf(sc[3][2], sc[3][3]));
            rm = fmaxf(fmaxf(m0v, m1v), fmaxf(m2v, m3v));
        } else {
            rm = -1e30f;
            #pragma unroll
            for (int i = 0; i < 4; ++i)
                #pragma unroll
                for (int r = 0; r < 4; ++r) {
                    const int key = kbase + i * 16 + lhi * 4 + r;
                    const float s = (key < Sb) ? sc[i][r] : -1e30f;
                    sc[i][r] = s;
                    rm = fmaxf(rm, s);
                }
        }
        rm = fmaxf(rm, __shfl_xor(rm, 16));
        rm = fmaxf(rm, __shfl_xor(rm, 32));

        if (!__all(rm <= m + 8.f)) {
            const float mnew = fmaxf(m, rm);
            const float corr = fexp2(m - mnew);
            l *= corr;
            #pragma unroll
            for (int i = 0; i < 4; ++i) acc[i] *= corr;
            m = mnew;
        }

        float ls = 0.f;
        #pragma unroll
        for (int i = 0; i < 4; ++i) {
            const float p0 = fexp2(sc[i][0] - m), p1 = fexp2(sc[i][1] - m);
            const float p2 = fexp2(sc[i][2] - m), p3 = fexp2(sc[i][3] - m);
            ls += (p0 + p1) + (p2 + p3);
            uint2 pp;
            pp.x = cvtpk(p0, p1);
            pp.y = cvtpk(p2, p3);
            *(uint2*)&Pl[w][llo * 72 + i * 16 + lhi * 4] = pp;
        }
        ls += __shfl_xor(ls, 16);
        ls += __shfl_xor(ls, 32);
        l += ls;

        __builtin_amdgcn_s_setprio(1);
        #pragma unroll
        for (int kk = 0; kk < 2; ++kk) {
            bf16x8 pb = *(const bf16x8*)&Pl[w][llo * 72 + kk * 32 + lhi * 8];
            #pragma unroll
            for (int i = 0; i < 4; ++i)
                acc[i] = __builtin_amdgcn_mfma_f32_16x16x32_bf16(av[i][kk], pb, acc[i], 0, 0, 0);
        }
        __builtin_amdgcn_s_setprio(0);
    }

    if (qi < Sb) {
        const size_t orow = (qi == 0) ? (size_t)(N + b) : (size_t)(start + qi - 1);
        const float invl = 1.f / l;
        #pragma unroll
        for (int i = 0; i < 4; ++i) {
            const int col0 = hh * 64 + i * 16 + lhi * 4;
            uint2 yy;
            yy.x = cvtpk(acc[i][0] * invl, acc[i][1] * invl);
            yy.y = cvtpk(acc[i][2] * invl, acc[i][3] * invl);
            *(uint2*)&outp[apack((int)orow, col0, 4)] = yy;
        }
    }
}

// ---------------- head ----------------

__global__ __launch_bounds__(256) void head_kernel(const float* __restrict__ h,
                                                   const float* __restrict__ w1,
                                                   const float* __restrict__ b1,
                                                   const float* __restrict__ w2,
                                                   const float* __restrict__ b2,
                                                   float* __restrict__ out, int N) {
    const int b = blockIdx.x;
    const int t = threadIdx.x;
    __shared__ float cls[DM];
    __shared__ float hid[DM];
    cls[t] = h[(size_t)(N + b) * DM + t];
    __syncthreads();
    float s = b1[t];
    for (int k = 0; k < DM; ++k) s = fmaf(cls[k], w1[t * DM + k], s);
    hid[t] = fmaxf(s, 0.f);
    __syncthreads();
    if (t < 2) {
        float o = b2[t];
        for (int k = 0; k < DM; ++k) o = fmaf(hid[k], w2[t * DM + k], o);
        out[b * 2 + t] = o;
    }
}

// ---------------- launch ----------------

extern "C" void kernel_launch(void* const* d_in, const int* in_sizes, int n_in,
                              void* d_out, int out_size, void* d_ws, size_t ws_size,
                              hipStream_t stream) {
    const float* dom_emb   = (const float*)d_in[0];
    const int*   dom_idx   = (const int*)d_in[1];
    const float* geometry  = (const float*)d_in[3];
    const float* in_w      = (const float*)d_in[4];
    const float* in_b      = (const float*)d_in[5];
    const float* geo_w     = (const float*)d_in[6];
    const float* geo_b     = (const float*)d_in[7];
    const float* cls_tok   = (const float*)d_in[8];
    const float* qkv_w     = (const float*)d_in[9];
    const float* qkv_b     = (const float*)d_in[10];
    const float* out_w     = (const float*)d_in[11];
    const float* out_b     = (const float*)d_in[12];
    const float* ln1_w     = (const float*)d_in[13];
    const float* ln1_b     = (const float*)d_in[14];
    const float* ln2_w     = (const float*)d_in[15];
    const float* ln2_b     = (const float*)d_in[16];
    const float* ff_w1     = (const float*)d_in[17];
    const float* ff_b1     = (const float*)d_in[18];
    const float* ff_w2     = (const float*)d_in[19];
    const float* ff_b2     = (const float*)d_in[20];
    const float* head_w1   = (const float*)d_in[21];
    const float* head_b1   = (const float*)d_in[22];
    const float* head_w2   = (const float*)d_in[23];
    const float* head_b2   = (const float*)d_in[24];
    float* outp = (float*)d_out;

    const int N  = in_sizes[0] / D_INPUT;      // 65536
    const int T  = N + BEV;                    // 65664
    const int TP = ((T + 255) / 256) * 256;    // 65792 = 1028*64

    // workspace layout (bytes)
    char* base = (char*)d_ws;
    size_t off = 0;
    int* counts = (int*)(base + off);          off += 1024;
    int* starts = (int*)(base + off);          off += 1024;
    u16*   Web  = (u16*)(base + off);          off += (size_t)256 * 384 * 2;
    float* be   = (float*)(base + off);        off += 1024;
    u16*   wq   = (u16*)(base + off);          off += (size_t)NLAYERS * 768 * 256 * 2;
    u16*   wo   = (u16*)(base + off);          off += (size_t)NLAYERS * 256 * 256 * 2;
    u16*   w1b  = (u16*)(base + off);          off += (size_t)NLAYERS * 1024 * 256 * 2;
    u16*   w2b  = (u16*)(base + off);          off += (size_t)NLAYERS * 256 * 1024 * 2;
    int*   r2bs = (int*)(base + off);          off += ((size_t)TP * 4 + 255) & ~255ULL;
    float* h    = (float*)(base + off);        off += (size_t)TP * DM * 4;    // 67.4 MB
    u16*   xb   = (u16*)(base + off);          off += (size_t)TP * DM * 2;    // 33.7 MB (packed)
    const size_t qb_sz  = (size_t)TP * 256 * 2;                          // 33.7 MB
    const size_t kvt_sz = (size_t)(BEV + 1) * 4 * 2 * KT * 4096 * 2;     // 84.6 MB
    const size_t big2   = qb_sz + kvt_sz;                                // 118.3 MB
    const size_t ffm_sz = (size_t)TP * 1024 * 2;                         // 134.7 MB (full)
    char* bigc = base + off;
    // runtime choice: single-chunk FF if workspace allows (deterministic per run)
    const bool ff_single = ws_size >= off + (ffm_sz > big2 ? ffm_sz : big2);
    off += ff_single ? (ffm_sz > big2 ? ffm_sz : big2) : big2;

    u16* Ab   = (u16*)bigc;                    // packed embed A (prep phase only)
    u16* Qbuf = (u16*)bigc;
    u16* KVt  = (u16*)(bigc + qb_sz);
    u16* ffm  = (u16*)bigc;                    // packed FF mid (full or TP/2 chunk)

    if (ws_size < off) {
        beacon_kernel<<<1, 256, 0, stream>>>(outp, out_size, (float)(ws_size >> 20));
        return;
    }

    // ---- weights: bf16 + fragment packing ----
    {
        const int ntot = NLAYERS * (768 * 256 + 256 * 256 + 1024 * 256 + 256 * 1024);
        cvt4p_kernel<<<(ntot + 255) / 256, 256, 0, stream>>>(
            qkv_w, out_w, ff_w1, ff_w2, wq, wo, w1b, w2b);
    }
    prep_w_kernel<<<(256 * 384 + 255) / 256, 256, 0, stream>>>(in_w, geo_w, in_b, geo_b, Web, be);

    // ---- event bookkeeping ----
    starts_kernel<<<1, 256, 0, stream>>>(dom_idx, counts, starts, N);
    r2bs_kernel<<<(TP + 255) / 256, 256, 0, stream>>>(dom_idx, starts, r2bs, N, TP);

    // ---- embed ----
    prep_a_kernel<<<(int)(((size_t)N * 96 + 255) / 256), 256, 0, stream>>>(dom_emb, geometry, Ab, N);
    pgemm_kernel<0><<<dim3(1, N / 64), 256, 0, stream>>>(
        Ab, Web, be, h, nullptr, nullptr, nullptr, 6);
    cls_kernel<<<BEV, DM, 0, stream>>>(cls_tok, h, N);

    // ---- transformer layers ----
    ln_kernel<<<TP / 4, 256, 0, stream>>>(h, ln1_w, ln1_b, xb, TP);
    for (int l = 0; l < NLAYERS; ++l) {
        pgemm_kernel<1><<<dim3(3, TP / 64), 256, 0, stream>>>(
            xb, wq + (size_t)l * 768 * 256, qkv_b + l * 768, nullptr, Qbuf, KVt, r2bs, 4);
        mattn_kernel<<<8 * KT * (BEV * NHEADS / 8), 256, 0, stream>>>(
            Qbuf, KVt, counts, starts, xb, N);
        mgemmln_kernel<<<TP / 64, 256, 0, stream>>>(
            xb, wo + (size_t)l * 256 * 256, out_b + l * DM, h,
            ln2_w + l * DM, ln2_b + l * DM, xb, 4);
        const int lnx = (l + 1 < NLAYERS) ? (l + 1) : l;   // dummy LN for last layer
        if (ff_single) {
            pgemm_kernel<2><<<dim3(4, TP / 64), 256, 0, stream>>>(
                xb, w1b + (size_t)l * DFF * 256, ff_b1 + l * DFF, nullptr, ffm,
                nullptr, nullptr, 4);
            mgemmln_kernel<<<TP / 64, 256, 0, stream>>>(
                ffm, w2b + (size_t)l * 256 * DFF, ff_b2 + l * DM, h,
                ln1_w + lnx * DM, ln1_b + lnx * DM, xb, 16);
        } else {
            for (int c = 0; c < 2; ++c) {
                const int r0 = c * (TP / 2);
                const u16* xc = xb + ((size_t)(r0 >> 4)) * 4 * 1024;
                pgemm_kernel<2><<<dim3(4, TP / 128), 256, 0, stream>>>(
                    xc, w1b + (size_t)l * DFF * 256, ff_b1 + l * DFF, nullptr, ffm,
                    nullptr, nullptr, 4);
                mgemmln_kernel<<<TP / 128, 256, 0, stream>>>(
                    ffm, w2b + (size_t)l * 256 * DFF, ff_b2 + l * DM, h + (size_t)r0 * DM,
                    ln1_w + lnx * DM, ln1_b + lnx * DM,
                    xb + ((size_t)(r0 >> 4)) * 4 * 1024, 16);
            }
        }
    }

    // ---- head ----
    head_kernel<<<BEV, DM, 0, stream>>>(h, head_w1, head_b1, head_w2, head_b2, outp, N);
}